// Round 14
// baseline (505.620 us; speedup 1.0000x reference)
//
#include <hip/hip_runtime.h>

#define D_MODEL 1024
#define NHEAD 16
#define LN_EPS 1e-5f
#define CHUNK 32
#define S_LEN 4096
#define NCH (S_LEN / CHUNK)   // 128

typedef unsigned short u16;
typedef __attribute__((ext_vector_type(8))) short short8;
typedef __attribute__((ext_vector_type(4))) float f32x4;

__device__ __forceinline__ u16 f2b(float f) {
  unsigned u = __builtin_bit_cast(unsigned, f);
  u += 0x7FFFu + ((u >> 16) & 1u);   // RNE
  return (u16)(u >> 16);
}
__device__ __forceinline__ float b2f(u16 s) {
  return __builtin_bit_cast(float, ((unsigned)s) << 16);
}

// ---------------- fused fp32->bf16 convert (x + 4 weights) + lam + cnt reset ----------------
__device__ __forceinline__ ushort4 cvt4(float4 f) {
  ushort4 o; o.x = f2b(f.x); o.y = f2b(f.y); o.z = f2b(f.z); o.w = f2b(f.w);
  return o;
}
__global__ __launch_bounds__(256) void cvt_all(
    const float4* __restrict__ x,  const float4* __restrict__ wq,
    const float4* __restrict__ wv, const float4* __restrict__ wg,
    const float4* __restrict__ wo, ushort4* __restrict__ xb,
    ushort4* __restrict__ wqvg, ushort4* __restrict__ wob,
    const float* __restrict__ beta, float* __restrict__ lam,
    unsigned* __restrict__ cnt, int nx4, int nw4) {
  int i = blockIdx.x * blockDim.x + threadIdx.x;
  int stride = gridDim.x * blockDim.x;
  if (blockIdx.x == 0 && threadIdx.x == 0) *cnt = 0u;   // deterministic per call
  if (blockIdx.x == 0 && threadIdx.x < NHEAD) {
    float l = 1.f / (1.f + __expf(-beta[threadIdx.x]));
    lam[threadIdx.x] = l;                  // lambda
    lam[NHEAD + threadIdx.x] = __log2f(l); // log2(lambda)
  }
  for (int j = i; j < nx4; j += stride) xb[j] = cvt4(x[j]);
  for (int j = i; j < nw4; j += stride) wqvg[j] = cvt4(wq[j]);
  for (int j = i; j < nw4; j += stride) wqvg[nw4 + j] = cvt4(wv[j]);
  for (int j = i; j < nw4; j += stride) wqvg[2 * nw4 + j] = cvt4(wg[j]);
  for (int j = i; j < nw4; j += stride) wob[j] = cvt4(wo[j]);
}

// ============ 256x256 tile, BK=64, 2-dbuf pipelined GEMM (frag-lead, r6) ============
// Measured best: QVG 99.3us, MfmaUtil 47%, bank-conflicts 0, FETCH 73.9MB.
// Survived alternatives (all measured, all reverted): r2 4-phase BK=32 (conflicts),
// r4 8-phase lockstep (-14%), r8 XCD swizzle (FETCH 2.7x), r12 256x128 3-blk/CU.
// + SCAN epilogue (r11): in-register intra-chunk EMA prefix for v-columns.
// + r14: carry-prefix pass (old scan_carry kernel) fused into the tail — the
// LAST carry-writing block (device atomic counter, release/acquire fences)
// performs the 128-step chunk-prefix scan; hidden under remaining g-blocks.

__device__ __forceinline__ void glds16(const u16* g, const u16* l) {
  __builtin_amdgcn_global_load_lds(
      (const __attribute__((address_space(1))) unsigned*)g,
      (__attribute__((address_space(3))) unsigned*)l, 16, 0, 0);
}

#define BAR() asm volatile("s_barrier" ::: "memory")
#define SB0() __builtin_amdgcn_sched_barrier(0)

template <typename OutT, bool CARRY>
__global__ __launch_bounds__(512, 2) void gemm256(const u16* __restrict__ X,
                                                  const u16* __restrict__ W,
                                                  OutT* __restrict__ Out,
                                                  float* __restrict__ carry,
                                                  const float* __restrict__ lamlog,
                                                  unsigned* __restrict__ cnt,
                                                  int M, int N, int K) {
  __shared__ u16 sm[8][8192];   // unit = d*4 + ab*2 + h ; 16 KB each
  __shared__ unsigned lastdone;
  const int tid = threadIdx.x;
  const int lane = tid & 63;
  const int wave = tid >> 6;              // 0..7
  const int ln15 = lane & 15, lh = lane >> 4;
  const int wr = wave >> 2, wc = wave & 3;
  const int bm = blockIdx.x * 256, bn = blockIdx.y * 256;
  const int NT = K >> 6;                  // K-tiles of 64 (>= 3)

  // ---- staging source (pre-swizzled global 16B-chunk within 128B row) ----
  const int srow = tid >> 3;                              // 0..63
  const int scol = ((tid & 7) ^ (srow & 7)) << 3;         // u16 col
  const u16* Asrc = X + (size_t)(bm + srow) * K + scol;
  const u16* Bsrc = W + (size_t)(bn + srow) * K + scol;
  const int ldsw = wave * 512;            // wave's u16 offset inside a unit

#define STAGE(u, h, tile, src)                                          \
  { const u16* _g = (src) + (size_t)((h) * 128) * K + (tile) * 64;      \
    glds16(_g,                  &sm[u][ldsw]);                          \
    glds16(_g + (size_t)64 * K, &sm[u][ldsw + 4096]); }

  // ---- ds_read bases (swizzled) ----
  const char* smb = (const char*)&sm[0][0];
  const char* Ard = smb + wr * 16384 + ln15 * 128;
  const char* Brd = smb + (2 + (wc >> 1)) * 16384 + ((wc & 1) * 64 + ln15) * 128;
  const int swz0 = ((lh ^ (ln15 & 7)) << 4);              // ks=0 chunk
  const int swz1 = (((4 + lh) ^ (ln15 & 7)) << 4);        // ks=1 chunk

#define RD_A(DB, MM, S) (*(const short8*)(Ard + (DB) + (MM) * 2048 + (S)))
#define RD_B(DB, NN, S) (*(const short8*)(Brd + (DB) + (NN) * 2048 + (S)))

  f32x4 acc[8][4];
  f32x4 zero = {0.f, 0.f, 0.f, 0.f};
  #pragma unroll
  for (int m = 0; m < 8; ++m)
    #pragma unroll
    for (int n = 0; n < 4; ++n) acc[m][n] = zero;

  short8 a[8][2], b[4][2];

#define MFMA_Q(M0, N0)                                                        \
  SB0();                                                                      \
  __builtin_amdgcn_s_setprio(1);                                              \
  _Pragma("unroll")                                                           \
  for (int m = (M0); m < (M0) + 4; ++m)                                       \
    _Pragma("unroll")                                                         \
    for (int n = (N0); n < (N0) + 2; ++n) {                                   \
      acc[m][n] = __builtin_amdgcn_mfma_f32_16x16x32_bf16(a[m][0], b[n][0], acc[m][n], 0, 0, 0); \
      acc[m][n] = __builtin_amdgcn_mfma_f32_16x16x32_bf16(a[m][1], b[n][1], acc[m][n], 0, 0, 0); \
    }                                                                         \
  __builtin_amdgcn_s_setprio(0);                                              \
  SB0();

  // ---- prologue ----
  STAGE(0, 0, 0, Asrc); STAGE(1, 1, 0, Asrc);
  STAGE(2, 0, 0, Bsrc); STAGE(3, 1, 0, Bsrc);
  STAGE(4, 0, 1, Asrc); STAGE(5, 1, 1, Asrc);
  asm volatile("s_waitcnt vmcnt(4)" ::: "memory");   // tile0 landed; A(1) flying
  BAR();
  #pragma unroll
  for (int m = 0; m < 4; ++m) { a[m][0] = RD_A(0, m, swz0); a[m][1] = RD_A(0, m, swz1); }
  #pragma unroll
  for (int n = 0; n < 4; ++n) { b[n][0] = RD_B(0, n, swz0); b[n][1] = RD_B(0, n, swz1); }

  for (int t = 0; t < NT; ++t) {
    const int d = t & 1;
    const int db = d * 65536;
    const int odb = (d ^ 1) * 65536;
    const int od = (d ^ 1) * 4;
    const int sd = d * 4;
    const int tB = (t + 1 < NT) ? t + 1 : NT - 1;
    const int tA = (t + 2 < NT) ? t + 2 : NT - 1;

    // ---- ph1: read a45(t); stage Bh0(t+1); MFMA Q1 = A0 x B0 ----
    a[4][0] = RD_A(db, 4, swz0); a[4][1] = RD_A(db, 4, swz1);
    a[5][0] = RD_A(db, 5, swz0); a[5][1] = RD_A(db, 5, swz1);
    STAGE(od + 2, 0, tB, Bsrc);
    MFMA_Q(0, 0)

    // ---- ph2: read a67(t); stage Bh1(t+1); MFMA Q2 = A0 x B1 ----
    a[6][0] = RD_A(db, 6, swz0); a[6][1] = RD_A(db, 6, swz1);
    a[7][0] = RD_A(db, 7, swz0); a[7][1] = RD_A(db, 7, swz1);
    STAGE(od + 3, 1, tB, Bsrc);
    MFMA_Q(0, 2)
    asm volatile("s_waitcnt vmcnt(4)" ::: "memory");
    BAR();

    // ---- ph3: read a03(t+1); MFMA Q3 = A1 x B1; stage Ah0(t+2) ----
    #pragma unroll
    for (int m = 0; m < 4; ++m) { a[m][0] = RD_A(odb, m, swz0); a[m][1] = RD_A(odb, m, swz1); }
    MFMA_Q(4, 2)
    STAGE(sd + 0, 0, tA, Asrc);
    asm volatile("s_waitcnt vmcnt(2)" ::: "memory");   // B(t+1) landed; Ah0(t+2) flying
    BAR();

    // ---- ph4: read b23(t+1); MFMA Q4 = A1 x B0; read b01(t+1); stage Ah1(t+2) ----
    b[2][0] = RD_B(odb, 2, swz0); b[2][1] = RD_B(odb, 2, swz1);
    b[3][0] = RD_B(odb, 3, swz0); b[3][1] = RD_B(odb, 3, swz1);
    MFMA_Q(4, 0)
    b[0][0] = RD_B(odb, 0, swz0); b[0][1] = RD_B(odb, 0, swz1);
    b[1][0] = RD_B(odb, 1, swz0); b[1][1] = RD_B(odb, 1, swz1);
    STAGE(sd + 1, 1, tA, Asrc);
  }
#undef STAGE
#undef RD_A
#undef RD_B
#undef MFMA_Q

  // ---- epilogue 0 (CARRY, v-columns): in-register intra-chunk EMA prefix ----
  if constexpr (CARRY) {
    if (bn >= 1024 && bn < 2048) {
      const float l2h = lamlog[((bn - 1024) + wc * 64) >> 6];
      const float lp1 = exp2f(l2h);
      const float lp2 = lp1 * lp1, lp3 = lp2 * lp1, lp4 = lp2 * lp2;
      const float l8 = lp4 * lp4;
      const float lpl = exp2f(l2h * (float)(4 * lh));   // lam^{4*lh}
      #pragma unroll
      for (int q = 0; q < 4; ++q)
        #pragma unroll
        for (int n = 0; n < 4; ++n) {
          f32x4 A0 = acc[2 * q][n], A1 = acc[2 * q + 1][n];
          A0[1] += lp1 * A0[0]; A0[2] += lp1 * A0[1]; A0[3] += lp1 * A0[2];
          A1[1] += lp1 * A1[0]; A1[2] += lp1 * A1[1]; A1[3] += lp1 * A1[2];
          float S = A0[3], x;
          x = __shfl_up(S, 16); if (lh >= 1) S += lp4 * x;
          x = __shfl_up(S, 32); if (lh >= 2) S += l8 * x;
          float Xc = __shfl_up(S, 16); Xc = (lh >= 1) ? Xc : 0.f;
          A0[0] += lp1 * Xc; A0[1] += lp2 * Xc; A0[2] += lp3 * Xc; A0[3] += lp4 * Xc;
          float f15 = __shfl(A0[3], 48 + ln15);
          S = A1[3];
          x = __shfl_up(S, 16); if (lh >= 1) S += lp4 * x;
          x = __shfl_up(S, 32); if (lh >= 2) S += l8 * x;
          Xc = __shfl_up(S, 16); Xc = (lh >= 1) ? Xc : 0.f;
          Xc += lpl * f15;
          A1[0] += lp1 * Xc; A1[1] += lp2 * Xc; A1[2] += lp3 * Xc; A1[3] += lp4 * Xc;
          acc[2 * q][n] = A0; acc[2 * q + 1][n] = A1;
        }
    }
  }

  // ---- epilogue 1: C write (v-blocks now hold the local prefix s) ----
  #pragma unroll
  for (int m = 0; m < 8; ++m)
    #pragma unroll
    for (int n = 0; n < 4; ++n)
      #pragma unroll
      for (int r = 0; r < 4; ++r) {
        int row = bm + wr * 128 + m * 16 + lh * 4 + r;   // C/D: row=(lane>>4)*4+reg
        int col = bn + wc * 64 + n * 16 + ln15;          //      col=lane&15
        float vv = acc[m][n][r];
        if constexpr (sizeof(OutT) == 2) Out[(size_t)row * N + col] = f2b(vv);
        else                             Out[(size_t)row * N + col] = vv;
      }

  // ---- epilogue 2: chunk totals = prefix at row 31 (lh==3, odd half, r==3) ----
  if constexpr (CARRY) {
    if (bn >= 1024 && bn < 2048) {
      if (lh == 3) {
        const int bidx = bm >> 12;                         // batch (4096 rows each)
        const int chunkbase = ((bm & 4095) >> 5) + wr * 4; // 32-row chunks
        const int colbase = (bn - 1024) + wc * 64;         // v-col base
        #pragma unroll
        for (int q = 0; q < 4; ++q)
          #pragma unroll
          for (int n = 0; n < 4; ++n)
            carry[(size_t)(bidx * NCH + chunkbase + q) * D_MODEL +
                  colbase + n * 16 + ln15] = acc[2 * q + 1][n][3];
      }

      // ---- epilogue 3 (r14): last carry block performs the chunk-prefix scan
      // c_j = lam^CHUNK * c_{j-1} + total_j over all B*D_MODEL columns.
      __threadfence();                       // release: carry stores visible
      if (tid == 0) lastdone = atomicAdd(cnt, 1u);
      __syncthreads();
      if (lastdone == 255u) {                // all 256 carry blocks done
        __threadfence();                     // acquire
        float cc[8], lC[8];
        #pragma unroll
        for (int k = 0; k < 8; ++k) {
          int c = tid + (k << 9);            // c in [0, 4096): b*1024 + col
          lC[k] = exp2f(lamlog[(c & 1023) >> 6] * (float)CHUNK);
          cc[k] = 0.f;
        }
        for (int j = 0; j < NCH; ++j) {
          #pragma unroll
          for (int k = 0; k < 8; ++k) {
            int c = tid + (k << 9);
            size_t a2 = ((size_t)((c >> 10) * NCH + j)) * D_MODEL + (c & 1023);
            cc[k] = lC[k] * cc[k] + carry[a2];
            carry[a2] = cc[k];
          }
        }
      }
    }
  }
}

// ---------------- row-parallel q*state + LayerNorm + SiLU gate ----------------
// One block per row; v-slot of qvg already holds the intra-chunk prefix s_t,
// so st = s_t + lam^{tl+1} * carry[j-1] — no serial dependence anywhere.
__global__ __launch_bounds__(256) void ew_ln(const u16* __restrict__ qvg,
    const float* __restrict__ carry, const float* __restrict__ lam,
    const float* __restrict__ gamma, const float* __restrict__ lbeta,
    u16* __restrict__ yout, int nch, int ld) {
  int row = blockIdx.x;
  int b = row >> 12;                      // S = 4096
  int srow = row & 4095;
  int j = srow >> 5, tl = srow & 31;      // CHUNK = 32
  int tid = threadIdx.x;
  int col0 = tid * 4;
  size_t rb = (size_t)row * ld;

  ushort4 qu = *(const ushort4*)(qvg + rb + col0);
  ushort4 su = *(const ushort4*)(qvg + rb + D_MODEL + col0);
  float st[4] = {b2f(su.x), b2f(su.y), b2f(su.z), b2f(su.w)};
  if (j > 0) {
    float p = exp2f(lam[NHEAD + (col0 >> 6)] * (float)(tl + 1));
    const float4 c4 = *(const float4*)(carry + ((size_t)(b * nch + j - 1)) * D_MODEL + col0);
    st[0] += p * c4.x; st[1] += p * c4.y; st[2] += p * c4.z; st[3] += p * c4.w;
  }
  float q[4] = {b2f(qu.x), b2f(qu.y), b2f(qu.z), b2f(qu.w)};
  float y[4];
  float sum = 0.f, sumsq = 0.f;
  #pragma unroll
  for (int i = 0; i < 4; ++i) {
    y[i] = q[i] * st[i];
    sum += y[i];
    sumsq += y[i] * y[i];
  }
  #pragma unroll
  for (int off = 32; off > 0; off >>= 1) {
    sum += __shfl_down(sum, off);
    sumsq += __shfl_down(sumsq, off);
  }
  __shared__ float red[8];
  int ln = tid & 63, wv = tid >> 6;
  if (ln == 0) { red[wv] = sum; red[4 + wv] = sumsq; }
  __syncthreads();
  sum = red[0] + red[1] + red[2] + red[3];
  sumsq = red[4] + red[5] + red[6] + red[7];
  float mu = sum * (1.f / 1024.f);
  float var = sumsq * (1.f / 1024.f) - mu * mu;
  float rstd = rsqrtf(var + LN_EPS);

  float4 gm = *(const float4*)(gamma + col0);
  float4 bt = *(const float4*)(lbeta + col0);
  ushort4 gu = *(const ushort4*)(qvg + rb + 2 * D_MODEL + col0);
  float gv[4]  = {b2f(gu.x), b2f(gu.y), b2f(gu.z), b2f(gu.w)};
  float gmv[4] = {gm.x, gm.y, gm.z, gm.w};
  float btv[4] = {bt.x, bt.y, bt.z, bt.w};
  u16 ov[4];
  #pragma unroll
  for (int i = 0; i < 4; ++i) {
    float gate = gv[i] / (1.f + __expf(-gv[i]));   // SiLU
    float oo = ((y[i] - mu) * rstd * gmv[i] + btv[i]) * gate;
    ov[i] = f2b(oo);
  }
  ushort4 o; o.x = ov[0]; o.y = ov[1]; o.z = ov[2]; o.w = ov[3];
  *(ushort4*)(yout + (size_t)row * D_MODEL + col0) = o;
}

extern "C" void kernel_launch(void* const* d_in, const int* in_sizes, int n_in,
                              void* d_out, int out_size, void* d_ws, size_t ws_size,
                              hipStream_t stream) {
  const float* x     = (const float*)d_in[0];
  const float* Wq    = (const float*)d_in[1];
  const float* Wv    = (const float*)d_in[2];
  const float* Wo    = (const float*)d_in[3];
  const float* Wg    = (const float*)d_in[4];
  const float* beta  = (const float*)d_in[5];
  const float* gamma = (const float*)d_in[6];
  const float* lbeta = (const float*)d_in[7];
  float* out = (float*)d_out;

  const int BS = in_sizes[0] / D_MODEL;     // 16384
  const int B = BS / S_LEN;                  // 4
  const int nch = NCH;                       // 128
  const size_t nx = (size_t)BS * D_MODEL;
  const size_t nw = (size_t)D_MODEL * D_MODEL;
  const int N3 = 3 * D_MODEL;                // 3072

  char* w = (char*)d_ws;
  u16* xb   = (u16*)w;  w += nx * 2;
  u16* wqvg = (u16*)w;  w += 3 * nw * 2;     // packed [Wq;Wv;Wg] rows
  u16* wob  = (u16*)w;  w += nw * 2;
  u16* qvg  = (u16*)w;  w += (size_t)BS * N3 * 2;   // packed [q|s|g] per row
  u16* yb   = (u16*)w;  w += nx * 2;
  float* carry = (float*)w;  w += (size_t)B * nch * D_MODEL * 4;
  float* lam = (float*)w;   w += 256;        // lam[16] + log2lam[16] + pad
  unsigned* cnt = (unsigned*)w;

  cvt_all<<<2048, 256, 0, stream>>>((const float4*)x, (const float4*)Wq,
      (const float4*)Wv, (const float4*)Wg, (const float4*)Wo,
      (ushort4*)xb, (ushort4*)wqvg, (ushort4*)wob, beta, lam, cnt,
      (int)(nx / 4), (int)(nw / 4));

  dim3 g1(BS / 256, N3 / 256);      // 64 x 12
  gemm256<u16, true><<<g1, 512, 0, stream>>>(xb, wqvg, qvg, carry, lam + NHEAD,
                                             cnt, BS, N3, D_MODEL);

  ew_ln<<<BS, 256, 0, stream>>>(qvg, carry, lam, gamma, lbeta, yb, nch, N3);

  dim3 g2(BS / 256, D_MODEL / 256); // 64 x 4
  gemm256<float, false><<<g2, 512, 0, stream>>>(yb, wob, out, nullptr, nullptr,
                                                nullptr, BS, D_MODEL, D_MODEL);
}

// Round 15
// 224.196 us; speedup vs baseline: 2.2553x; 2.2553x over previous
//
#include <hip/hip_runtime.h>

#define D_MODEL 1024
#define NHEAD 16
#define LN_EPS 1e-5f
#define CHUNK 32
#define S_LEN 4096
#define NCH (S_LEN / CHUNK)   // 128

typedef unsigned short u16;
typedef __attribute__((ext_vector_type(8))) short short8;
typedef __attribute__((ext_vector_type(4))) float f32x4;

__device__ __forceinline__ u16 f2b(float f) {
  unsigned u = __builtin_bit_cast(unsigned, f);
  u += 0x7FFFu + ((u >> 16) & 1u);   // RNE
  return (u16)(u >> 16);
}
__device__ __forceinline__ float b2f(u16 s) {
  return __builtin_bit_cast(float, ((unsigned)s) << 16);
}

// ---------------- fused fp32->bf16 convert (x + 4 weights) + lam ----------------
__device__ __forceinline__ ushort4 cvt4(float4 f) {
  ushort4 o; o.x = f2b(f.x); o.y = f2b(f.y); o.z = f2b(f.z); o.w = f2b(f.w);
  return o;
}
__global__ __launch_bounds__(256) void cvt_all(
    const float4* __restrict__ x,  const float4* __restrict__ wq,
    const float4* __restrict__ wv, const float4* __restrict__ wg,
    const float4* __restrict__ wo, ushort4* __restrict__ xb,
    ushort4* __restrict__ wqvg, ushort4* __restrict__ wob,
    const float* __restrict__ beta, float* __restrict__ lam,
    int nx4, int nw4) {
  int i = blockIdx.x * blockDim.x + threadIdx.x;
  int stride = gridDim.x * blockDim.x;
  if (blockIdx.x == 0 && threadIdx.x < NHEAD) {
    float l = 1.f / (1.f + __expf(-beta[threadIdx.x]));
    lam[threadIdx.x] = l;                  // lambda
    lam[NHEAD + threadIdx.x] = __log2f(l); // log2(lambda)
  }
  for (int j = i; j < nx4; j += stride) xb[j] = cvt4(x[j]);
  for (int j = i; j < nw4; j += stride) wqvg[j] = cvt4(wq[j]);
  for (int j = i; j < nw4; j += stride) wqvg[nw4 + j] = cvt4(wv[j]);
  for (int j = i; j < nw4; j += stride) wqvg[2 * nw4 + j] = cvt4(wg[j]);
  for (int j = i; j < nw4; j += stride) wob[j] = cvt4(wo[j]);
}

// ============ 256x256 tile, BK=64, 2-dbuf pipelined GEMM (frag-lead, r6) ============
// Measured best: QVG 99.3us, MfmaUtil 47%, bank-conflicts 0, FETCH 73.9MB.
// Survived alternatives (all measured, all reverted): r2 4-phase BK=32 (conflicts),
// r4 8-phase lockstep (-14%), r8 XCD swizzle (FETCH 2.7x), r12 256x128 3-blk/CU,
// r14 fused scan tail (single-block alias-serialized scan = +330us exposed tail).
// NO XCD swizzle. Swizzle: 16B chunk c within each 128B row stored at c^(row&7)
// (pre-swizzled global source + XOR'd ds_read addr) — 0 conflicts measured.
// + SCAN epilogue (r11): in-register intra-chunk EMA prefix for v-columns;
// carry totals free from row-31 lanes. Downstream fully row-parallel.

__device__ __forceinline__ void glds16(const u16* g, const u16* l) {
  __builtin_amdgcn_global_load_lds(
      (const __attribute__((address_space(1))) unsigned*)g,
      (__attribute__((address_space(3))) unsigned*)l, 16, 0, 0);
}

#define BAR() asm volatile("s_barrier" ::: "memory")
#define SB0() __builtin_amdgcn_sched_barrier(0)

template <typename OutT, bool CARRY>
__global__ __launch_bounds__(512, 2) void gemm256(const u16* __restrict__ X,
                                                  const u16* __restrict__ W,
                                                  OutT* __restrict__ Out,
                                                  float* __restrict__ carry,
                                                  const float* __restrict__ lamlog,
                                                  int M, int N, int K) {
  __shared__ u16 sm[8][8192];   // unit = d*4 + ab*2 + h ; 16 KB each
  const int tid = threadIdx.x;
  const int lane = tid & 63;
  const int wave = tid >> 6;              // 0..7
  const int ln15 = lane & 15, lh = lane >> 4;
  const int wr = wave >> 2, wc = wave & 3;
  const int bm = blockIdx.x * 256, bn = blockIdx.y * 256;
  const int NT = K >> 6;                  // K-tiles of 64 (>= 3)

  // ---- staging source (pre-swizzled global 16B-chunk within 128B row) ----
  const int srow = tid >> 3;                              // 0..63
  const int scol = ((tid & 7) ^ (srow & 7)) << 3;         // u16 col
  const u16* Asrc = X + (size_t)(bm + srow) * K + scol;
  const u16* Bsrc = W + (size_t)(bn + srow) * K + scol;
  const int ldsw = wave * 512;            // wave's u16 offset inside a unit

#define STAGE(u, h, tile, src)                                          \
  { const u16* _g = (src) + (size_t)((h) * 128) * K + (tile) * 64;      \
    glds16(_g,                  &sm[u][ldsw]);                          \
    glds16(_g + (size_t)64 * K, &sm[u][ldsw + 4096]); }

  // ---- ds_read bases (swizzled) ----
  const char* smb = (const char*)&sm[0][0];
  const char* Ard = smb + wr * 16384 + ln15 * 128;
  const char* Brd = smb + (2 + (wc >> 1)) * 16384 + ((wc & 1) * 64 + ln15) * 128;
  const int swz0 = ((lh ^ (ln15 & 7)) << 4);              // ks=0 chunk
  const int swz1 = (((4 + lh) ^ (ln15 & 7)) << 4);        // ks=1 chunk

#define RD_A(DB, MM, S) (*(const short8*)(Ard + (DB) + (MM) * 2048 + (S)))
#define RD_B(DB, NN, S) (*(const short8*)(Brd + (DB) + (NN) * 2048 + (S)))

  f32x4 acc[8][4];
  f32x4 zero = {0.f, 0.f, 0.f, 0.f};
  #pragma unroll
  for (int m = 0; m < 8; ++m)
    #pragma unroll
    for (int n = 0; n < 4; ++n) acc[m][n] = zero;

  short8 a[8][2], b[4][2];

#define MFMA_Q(M0, N0)                                                        \
  SB0();                                                                      \
  __builtin_amdgcn_s_setprio(1);                                              \
  _Pragma("unroll")                                                           \
  for (int m = (M0); m < (M0) + 4; ++m)                                       \
    _Pragma("unroll")                                                         \
    for (int n = (N0); n < (N0) + 2; ++n) {                                   \
      acc[m][n] = __builtin_amdgcn_mfma_f32_16x16x32_bf16(a[m][0], b[n][0], acc[m][n], 0, 0, 0); \
      acc[m][n] = __builtin_amdgcn_mfma_f32_16x16x32_bf16(a[m][1], b[n][1], acc[m][n], 0, 0, 0); \
    }                                                                         \
  __builtin_amdgcn_s_setprio(0);                                              \
  SB0();

  // ---- prologue ----
  STAGE(0, 0, 0, Asrc); STAGE(1, 1, 0, Asrc);
  STAGE(2, 0, 0, Bsrc); STAGE(3, 1, 0, Bsrc);
  STAGE(4, 0, 1, Asrc); STAGE(5, 1, 1, Asrc);
  asm volatile("s_waitcnt vmcnt(4)" ::: "memory");   // tile0 landed; A(1) flying
  BAR();
  #pragma unroll
  for (int m = 0; m < 4; ++m) { a[m][0] = RD_A(0, m, swz0); a[m][1] = RD_A(0, m, swz1); }
  #pragma unroll
  for (int n = 0; n < 4; ++n) { b[n][0] = RD_B(0, n, swz0); b[n][1] = RD_B(0, n, swz1); }

  for (int t = 0; t < NT; ++t) {
    const int d = t & 1;
    const int db = d * 65536;
    const int odb = (d ^ 1) * 65536;
    const int od = (d ^ 1) * 4;
    const int sd = d * 4;
    const int tB = (t + 1 < NT) ? t + 1 : NT - 1;
    const int tA = (t + 2 < NT) ? t + 2 : NT - 1;

    // ---- ph1: read a45(t); stage Bh0(t+1); MFMA Q1 = A0 x B0 ----
    a[4][0] = RD_A(db, 4, swz0); a[4][1] = RD_A(db, 4, swz1);
    a[5][0] = RD_A(db, 5, swz0); a[5][1] = RD_A(db, 5, swz1);
    STAGE(od + 2, 0, tB, Bsrc);
    MFMA_Q(0, 0)

    // ---- ph2: read a67(t); stage Bh1(t+1); MFMA Q2 = A0 x B1 ----
    a[6][0] = RD_A(db, 6, swz0); a[6][1] = RD_A(db, 6, swz1);
    a[7][0] = RD_A(db, 7, swz0); a[7][1] = RD_A(db, 7, swz1);
    STAGE(od + 3, 1, tB, Bsrc);
    MFMA_Q(0, 2)
    asm volatile("s_waitcnt vmcnt(4)" ::: "memory");
    BAR();

    // ---- ph3: read a03(t+1); MFMA Q3 = A1 x B1; stage Ah0(t+2) ----
    #pragma unroll
    for (int m = 0; m < 4; ++m) { a[m][0] = RD_A(odb, m, swz0); a[m][1] = RD_A(odb, m, swz1); }
    MFMA_Q(4, 2)
    STAGE(sd + 0, 0, tA, Asrc);
    asm volatile("s_waitcnt vmcnt(2)" ::: "memory");   // B(t+1) landed; Ah0(t+2) flying
    BAR();

    // ---- ph4: read b23(t+1); MFMA Q4 = A1 x B0; read b01(t+1); stage Ah1(t+2) ----
    b[2][0] = RD_B(odb, 2, swz0); b[2][1] = RD_B(odb, 2, swz1);
    b[3][0] = RD_B(odb, 3, swz0); b[3][1] = RD_B(odb, 3, swz1);
    MFMA_Q(4, 0)
    b[0][0] = RD_B(odb, 0, swz0); b[0][1] = RD_B(odb, 0, swz1);
    b[1][0] = RD_B(odb, 1, swz0); b[1][1] = RD_B(odb, 1, swz1);
    STAGE(sd + 1, 1, tA, Asrc);
  }
#undef STAGE
#undef RD_A
#undef RD_B
#undef MFMA_Q

  // ---- epilogue 0 (CARRY, v-columns): in-register intra-chunk EMA prefix ----
  // Chunk q rows (within wave): m=2q holds rows lh*4+r, m=2q+1 rows 16+lh*4+r.
  if constexpr (CARRY) {
    if (bn >= 1024 && bn < 2048) {
      const float l2h = lamlog[((bn - 1024) + wc * 64) >> 6];
      const float lp1 = exp2f(l2h);
      const float lp2 = lp1 * lp1, lp3 = lp2 * lp1, lp4 = lp2 * lp2;
      const float l8 = lp4 * lp4;
      const float lpl = exp2f(l2h * (float)(4 * lh));   // lam^{4*lh}
      #pragma unroll
      for (int q = 0; q < 4; ++q)
        #pragma unroll
        for (int n = 0; n < 4; ++n) {
          f32x4 A0 = acc[2 * q][n], A1 = acc[2 * q + 1][n];
          // in-lane prefix over r (4 contiguous rows)
          A0[1] += lp1 * A0[0]; A0[2] += lp1 * A0[1]; A0[3] += lp1 * A0[2];
          A1[1] += lp1 * A1[0]; A1[2] += lp1 * A1[1]; A1[3] += lp1 * A1[2];
          // cross-lh scan (4 groups of 4 rows), ratio lam^4
          float S = A0[3], x;
          x = __shfl_up(S, 16); if (lh >= 1) S += lp4 * x;
          x = __shfl_up(S, 32); if (lh >= 2) S += l8 * x;
          float Xc = __shfl_up(S, 16); Xc = (lh >= 1) ? Xc : 0.f;  // S_{g-1}
          A0[0] += lp1 * Xc; A0[1] += lp2 * Xc; A0[2] += lp3 * Xc; A0[3] += lp4 * Xc;
          // full prefix through row 15 (lh=3, r=3 of first half)
          float f15 = __shfl(A0[3], 48 + ln15);
          // second half: same cross-lh scan + cross-half carry
          S = A1[3];
          x = __shfl_up(S, 16); if (lh >= 1) S += lp4 * x;
          x = __shfl_up(S, 32); if (lh >= 2) S += l8 * x;
          Xc = __shfl_up(S, 16); Xc = (lh >= 1) ? Xc : 0.f;
          Xc += lpl * f15;   // row 16+lh*4+r gets lam^{lh*4+r+1} * f15
          A1[0] += lp1 * Xc; A1[1] += lp2 * Xc; A1[2] += lp3 * Xc; A1[3] += lp4 * Xc;
          acc[2 * q][n] = A0; acc[2 * q + 1][n] = A1;
        }
    }
  }

  // ---- epilogue 1: C write (v-blocks now hold the local prefix s) ----
  #pragma unroll
  for (int m = 0; m < 8; ++m)
    #pragma unroll
    for (int n = 0; n < 4; ++n)
      #pragma unroll
      for (int r = 0; r < 4; ++r) {
        int row = bm + wr * 128 + m * 16 + lh * 4 + r;   // C/D: row=(lane>>4)*4+reg
        int col = bn + wc * 64 + n * 16 + ln15;          //      col=lane&15
        float vv = acc[m][n][r];
        if constexpr (sizeof(OutT) == 2) Out[(size_t)row * N + col] = f2b(vv);
        else                             Out[(size_t)row * N + col] = vv;
      }

  // ---- epilogue 2: chunk totals = prefix at row 31 (lh==3, odd half, r==3) ----
  if constexpr (CARRY) {
    if (bn >= 1024 && bn < 2048 && lh == 3) {
      const int bidx = bm >> 12;                         // batch (4096 rows each)
      const int chunkbase = ((bm & 4095) >> 5) + wr * 4; // 32-row chunks
      const int colbase = (bn - 1024) + wc * 64;         // v-col base
      #pragma unroll
      for (int q = 0; q < 4; ++q)
        #pragma unroll
        for (int n = 0; n < 4; ++n)
          carry[(size_t)(bidx * NCH + chunkbase + q) * D_MODEL +
                colbase + n * 16 + ln15] = acc[2 * q + 1][n][3];
    }
  }
}

// ---------------- carry prefix: c_j = lambda^CHUNK * c_{j-1} + total_j ----------------
__global__ void scan_carry(float* __restrict__ carry, const float* __restrict__ lam,
                           int B, int nch) {
  int idx = blockIdx.x * blockDim.x + threadIdx.x;
  if (idx >= B * D_MODEL) return;
  int b = idx >> 10, col = idx & (D_MODEL - 1);
  float lC = exp2f(lam[NHEAD + (col >> 6)] * (float)CHUNK);
  float c = 0.f;
  #pragma unroll 4
  for (int j = 0; j < nch; ++j) {
    size_t a = ((size_t)(b * nch + j)) * D_MODEL + col;
    c = lC * c + carry[a];
    carry[a] = c;
  }
}

// ---------------- row-parallel q*state + LayerNorm + SiLU gate ----------------
// One block per row; v-slot of qvg already holds the intra-chunk prefix s_t,
// so st = s_t + lam^{tl+1} * carry[j-1] — no serial dependence anywhere.
__global__ __launch_bounds__(256) void ew_ln(const u16* __restrict__ qvg,
    const float* __restrict__ carry, const float* __restrict__ lam,
    const float* __restrict__ gamma, const float* __restrict__ lbeta,
    u16* __restrict__ yout, int nch, int ld) {
  int row = blockIdx.x;
  int b = row >> 12;                      // S = 4096
  int srow = row & 4095;
  int j = srow >> 5, tl = srow & 31;      // CHUNK = 32
  int tid = threadIdx.x;
  int col0 = tid * 4;
  size_t rb = (size_t)row * ld;

  ushort4 qu = *(const ushort4*)(qvg + rb + col0);
  ushort4 su = *(const ushort4*)(qvg + rb + D_MODEL + col0);
  float st[4] = {b2f(su.x), b2f(su.y), b2f(su.z), b2f(su.w)};
  if (j > 0) {
    float p = exp2f(lam[NHEAD + (col0 >> 6)] * (float)(tl + 1));
    const float4 c4 = *(const float4*)(carry + ((size_t)(b * nch + j - 1)) * D_MODEL + col0);
    st[0] += p * c4.x; st[1] += p * c4.y; st[2] += p * c4.z; st[3] += p * c4.w;
  }
  float q[4] = {b2f(qu.x), b2f(qu.y), b2f(qu.z), b2f(qu.w)};
  float y[4];
  float sum = 0.f, sumsq = 0.f;
  #pragma unroll
  for (int i = 0; i < 4; ++i) {
    y[i] = q[i] * st[i];
    sum += y[i];
    sumsq += y[i] * y[i];
  }
  #pragma unroll
  for (int off = 32; off > 0; off >>= 1) {
    sum += __shfl_down(sum, off);
    sumsq += __shfl_down(sumsq, off);
  }
  __shared__ float red[8];
  int ln = tid & 63, wv = tid >> 6;
  if (ln == 0) { red[wv] = sum; red[4 + wv] = sumsq; }
  __syncthreads();
  sum = red[0] + red[1] + red[2] + red[3];
  sumsq = red[4] + red[5] + red[6] + red[7];
  float mu = sum * (1.f / 1024.f);
  float var = sumsq * (1.f / 1024.f) - mu * mu;
  float rstd = rsqrtf(var + LN_EPS);

  float4 gm = *(const float4*)(gamma + col0);
  float4 bt = *(const float4*)(lbeta + col0);
  ushort4 gu = *(const ushort4*)(qvg + rb + 2 * D_MODEL + col0);
  float gv[4]  = {b2f(gu.x), b2f(gu.y), b2f(gu.z), b2f(gu.w)};
  float gmv[4] = {gm.x, gm.y, gm.z, gm.w};
  float btv[4] = {bt.x, bt.y, bt.z, bt.w};
  u16 ov[4];
  #pragma unroll
  for (int i = 0; i < 4; ++i) {
    float gate = gv[i] / (1.f + __expf(-gv[i]));   // SiLU
    float oo = ((y[i] - mu) * rstd * gmv[i] + btv[i]) * gate;
    ov[i] = f2b(oo);
  }
  ushort4 o; o.x = ov[0]; o.y = ov[1]; o.z = ov[2]; o.w = ov[3];
  *(ushort4*)(yout + (size_t)row * D_MODEL + col0) = o;
}

extern "C" void kernel_launch(void* const* d_in, const int* in_sizes, int n_in,
                              void* d_out, int out_size, void* d_ws, size_t ws_size,
                              hipStream_t stream) {
  const float* x     = (const float*)d_in[0];
  const float* Wq    = (const float*)d_in[1];
  const float* Wv    = (const float*)d_in[2];
  const float* Wo    = (const float*)d_in[3];
  const float* Wg    = (const float*)d_in[4];
  const float* beta  = (const float*)d_in[5];
  const float* gamma = (const float*)d_in[6];
  const float* lbeta = (const float*)d_in[7];
  float* out = (float*)d_out;

  const int BS = in_sizes[0] / D_MODEL;     // 16384
  const int B = BS / S_LEN;                  // 4
  const int nch = NCH;                       // 128
  const size_t nx = (size_t)BS * D_MODEL;
  const size_t nw = (size_t)D_MODEL * D_MODEL;
  const int N3 = 3 * D_MODEL;                // 3072

  char* w = (char*)d_ws;
  u16* xb   = (u16*)w;  w += nx * 2;
  u16* wqvg = (u16*)w;  w += 3 * nw * 2;     // packed [Wq;Wv;Wg] rows
  u16* wob  = (u16*)w;  w += nw * 2;
  u16* qvg  = (u16*)w;  w += (size_t)BS * N3 * 2;   // packed [q|s|g] per row
  u16* yb   = (u16*)w;  w += nx * 2;
  float* carry = (float*)w;  w += (size_t)B * nch * D_MODEL * 4;
  float* lam = (float*)w;

  cvt_all<<<2048, 256, 0, stream>>>((const float4*)x, (const float4*)Wq,
      (const float4*)Wv, (const float4*)Wg, (const float4*)Wo,
      (ushort4*)xb, (ushort4*)wqvg, (ushort4*)wob, beta, lam,
      (int)(nx / 4), (int)(nw / 4));

  dim3 g1(BS / 256, N3 / 256);      // 64 x 12
  gemm256<u16, true><<<g1, 512, 0, stream>>>(xb, wqvg, qvg, carry, lam + NHEAD,
                                             BS, N3, D_MODEL);

  scan_carry<<<(B * D_MODEL + 255) / 256, 256, 0, stream>>>(carry, lam, B, nch);
  ew_ln<<<BS, 256, 0, stream>>>(qvg, carry, lam, gamma, lbeta, yb, nch, N3);

  dim3 g2(BS / 256, D_MODEL / 256); // 64 x 4
  gemm256<float, false><<<g2, 512, 0, stream>>>(yb, wob, out, nullptr, nullptr,
                                                BS, D_MODEL, D_MODEL);
}

// Round 16
// 222.846 us; speedup vs baseline: 2.2689x; 1.0061x over previous
//
#include <hip/hip_runtime.h>

#define D_MODEL 1024
#define NHEAD 16
#define LN_EPS 1e-5f
#define CHUNK 32
#define S_LEN 4096
#define NCH (S_LEN / CHUNK)   // 128

typedef unsigned short u16;
typedef __attribute__((ext_vector_type(8))) short short8;
typedef __attribute__((ext_vector_type(8))) unsigned short u16x8;
typedef __attribute__((ext_vector_type(4))) float f32x4;

__device__ __forceinline__ u16 f2b(float f) {
  unsigned u = __builtin_bit_cast(unsigned, f);
  u += 0x7FFFu + ((u >> 16) & 1u);   // RNE
  return (u16)(u >> 16);
}
__device__ __forceinline__ float b2f(u16 s) {
  return __builtin_bit_cast(float, ((unsigned)s) << 16);
}

// ---------------- fused fp32->bf16 convert (x + 4 weights) + lam ----------------
__device__ __forceinline__ ushort4 cvt4(float4 f) {
  ushort4 o; o.x = f2b(f.x); o.y = f2b(f.y); o.z = f2b(f.z); o.w = f2b(f.w);
  return o;
}
__global__ __launch_bounds__(256) void cvt_all(
    const float4* __restrict__ x,  const float4* __restrict__ wq,
    const float4* __restrict__ wv, const float4* __restrict__ wg,
    const float4* __restrict__ wo, ushort4* __restrict__ xb,
    ushort4* __restrict__ wqvg, ushort4* __restrict__ wob,
    const float* __restrict__ beta, float* __restrict__ lam,
    int nx4, int nw4) {
  int i = blockIdx.x * blockDim.x + threadIdx.x;
  int stride = gridDim.x * blockDim.x;
  if (blockIdx.x == 0 && threadIdx.x < NHEAD) {
    float l = 1.f / (1.f + __expf(-beta[threadIdx.x]));
    lam[threadIdx.x] = l;                  // lambda
    lam[NHEAD + threadIdx.x] = __log2f(l); // log2(lambda)
  }
  for (int j = i; j < nx4; j += stride) xb[j] = cvt4(x[j]);
  for (int j = i; j < nw4; j += stride) wqvg[j] = cvt4(wq[j]);
  for (int j = i; j < nw4; j += stride) wqvg[nw4 + j] = cvt4(wv[j]);
  for (int j = i; j < nw4; j += stride) wqvg[2 * nw4 + j] = cvt4(wg[j]);
  for (int j = i; j < nw4; j += stride) wob[j] = cvt4(wo[j]);
}

// ============ 256x256 tile, BK=64, 2-dbuf pipelined GEMM (frag-lead, r6) ============
// Measured best: QVG 99.3us, MfmaUtil 47%, bank-conflicts 0, FETCH 73.9MB.
// Survived alternatives (all measured, all reverted): r2 4-phase BK=32 (conflicts),
// r4 8-phase lockstep (-14%), r8 XCD swizzle (FETCH 2.7x), r12 256x128 3-blk/CU,
// r14 fused scan tail (single-block alias-serialized scan = +330us exposed tail).
// 32x32x16 MFMA conversion analyzed and rejected: A-frag read spans 32 rows ->
// inherent 4-way LDS conflict (+27% LDS) > -13% MFMA gain.
// NO XCD swizzle. Swizzle: 16B chunk c within each 128B row stored at c^(row&7)
// (pre-swizzled global source + XOR'd ds_read addr) — 0 conflicts measured.
// + SCAN epilogue (r11): in-register intra-chunk EMA prefix for v-columns;
// carry totals free from row-31 lanes. Downstream fully row-parallel.

__device__ __forceinline__ void glds16(const u16* g, const u16* l) {
  __builtin_amdgcn_global_load_lds(
      (const __attribute__((address_space(1))) unsigned*)g,
      (__attribute__((address_space(3))) unsigned*)l, 16, 0, 0);
}

#define BAR() asm volatile("s_barrier" ::: "memory")
#define SB0() __builtin_amdgcn_sched_barrier(0)

template <typename OutT, bool CARRY>
__global__ __launch_bounds__(512, 2) void gemm256(const u16* __restrict__ X,
                                                  const u16* __restrict__ W,
                                                  OutT* __restrict__ Out,
                                                  float* __restrict__ carry,
                                                  const float* __restrict__ lamlog,
                                                  int M, int N, int K) {
  __shared__ u16 sm[8][8192];   // unit = d*4 + ab*2 + h ; 16 KB each
  const int tid = threadIdx.x;
  const int lane = tid & 63;
  const int wave = tid >> 6;              // 0..7
  const int ln15 = lane & 15, lh = lane >> 4;
  const int wr = wave >> 2, wc = wave & 3;
  const int bm = blockIdx.x * 256, bn = blockIdx.y * 256;
  const int NT = K >> 6;                  // K-tiles of 64 (>= 3)

  // ---- staging source (pre-swizzled global 16B-chunk within 128B row) ----
  const int srow = tid >> 3;                              // 0..63
  const int scol = ((tid & 7) ^ (srow & 7)) << 3;         // u16 col
  const u16* Asrc = X + (size_t)(bm + srow) * K + scol;
  const u16* Bsrc = W + (size_t)(bn + srow) * K + scol;
  const int ldsw = wave * 512;            // wave's u16 offset inside a unit

#define STAGE(u, h, tile, src)                                          \
  { const u16* _g = (src) + (size_t)((h) * 128) * K + (tile) * 64;      \
    glds16(_g,                  &sm[u][ldsw]);                          \
    glds16(_g + (size_t)64 * K, &sm[u][ldsw + 4096]); }

  // ---- ds_read bases (swizzled) ----
  const char* smb = (const char*)&sm[0][0];
  const char* Ard = smb + wr * 16384 + ln15 * 128;
  const char* Brd = smb + (2 + (wc >> 1)) * 16384 + ((wc & 1) * 64 + ln15) * 128;
  const int swz0 = ((lh ^ (ln15 & 7)) << 4);              // ks=0 chunk
  const int swz1 = (((4 + lh) ^ (ln15 & 7)) << 4);        // ks=1 chunk

#define RD_A(DB, MM, S) (*(const short8*)(Ard + (DB) + (MM) * 2048 + (S)))
#define RD_B(DB, NN, S) (*(const short8*)(Brd + (DB) + (NN) * 2048 + (S)))

  f32x4 acc[8][4];
  f32x4 zero = {0.f, 0.f, 0.f, 0.f};
  #pragma unroll
  for (int m = 0; m < 8; ++m)
    #pragma unroll
    for (int n = 0; n < 4; ++n) acc[m][n] = zero;

  short8 a[8][2], b[4][2];

#define MFMA_Q(M0, N0)                                                        \
  SB0();                                                                      \
  __builtin_amdgcn_s_setprio(1);                                              \
  _Pragma("unroll")                                                           \
  for (int m = (M0); m < (M0) + 4; ++m)                                       \
    _Pragma("unroll")                                                         \
    for (int n = (N0); n < (N0) + 2; ++n) {                                   \
      acc[m][n] = __builtin_amdgcn_mfma_f32_16x16x32_bf16(a[m][0], b[n][0], acc[m][n], 0, 0, 0); \
      acc[m][n] = __builtin_amdgcn_mfma_f32_16x16x32_bf16(a[m][1], b[n][1], acc[m][n], 0, 0, 0); \
    }                                                                         \
  __builtin_amdgcn_s_setprio(0);                                              \
  SB0();

  // ---- prologue ----
  STAGE(0, 0, 0, Asrc); STAGE(1, 1, 0, Asrc);
  STAGE(2, 0, 0, Bsrc); STAGE(3, 1, 0, Bsrc);
  STAGE(4, 0, 1, Asrc); STAGE(5, 1, 1, Asrc);
  asm volatile("s_waitcnt vmcnt(4)" ::: "memory");   // tile0 landed; A(1) flying
  BAR();
  #pragma unroll
  for (int m = 0; m < 4; ++m) { a[m][0] = RD_A(0, m, swz0); a[m][1] = RD_A(0, m, swz1); }
  #pragma unroll
  for (int n = 0; n < 4; ++n) { b[n][0] = RD_B(0, n, swz0); b[n][1] = RD_B(0, n, swz1); }

  for (int t = 0; t < NT; ++t) {
    const int d = t & 1;
    const int db = d * 65536;
    const int odb = (d ^ 1) * 65536;
    const int od = (d ^ 1) * 4;
    const int sd = d * 4;
    const int tB = (t + 1 < NT) ? t + 1 : NT - 1;
    const int tA = (t + 2 < NT) ? t + 2 : NT - 1;

    // ---- ph1: read a45(t); stage Bh0(t+1); MFMA Q1 = A0 x B0 ----
    a[4][0] = RD_A(db, 4, swz0); a[4][1] = RD_A(db, 4, swz1);
    a[5][0] = RD_A(db, 5, swz0); a[5][1] = RD_A(db, 5, swz1);
    STAGE(od + 2, 0, tB, Bsrc);
    MFMA_Q(0, 0)

    // ---- ph2: read a67(t); stage Bh1(t+1); MFMA Q2 = A0 x B1 ----
    a[6][0] = RD_A(db, 6, swz0); a[6][1] = RD_A(db, 6, swz1);
    a[7][0] = RD_A(db, 7, swz0); a[7][1] = RD_A(db, 7, swz1);
    STAGE(od + 3, 1, tB, Bsrc);
    MFMA_Q(0, 2)
    asm volatile("s_waitcnt vmcnt(4)" ::: "memory");
    BAR();

    // ---- ph3: read a03(t+1); MFMA Q3 = A1 x B1; stage Ah0(t+2) ----
    #pragma unroll
    for (int m = 0; m < 4; ++m) { a[m][0] = RD_A(odb, m, swz0); a[m][1] = RD_A(odb, m, swz1); }
    MFMA_Q(4, 2)
    STAGE(sd + 0, 0, tA, Asrc);
    asm volatile("s_waitcnt vmcnt(2)" ::: "memory");   // B(t+1) landed; Ah0(t+2) flying
    BAR();

    // ---- ph4: read b23(t+1); MFMA Q4 = A1 x B0; read b01(t+1); stage Ah1(t+2) ----
    b[2][0] = RD_B(odb, 2, swz0); b[2][1] = RD_B(odb, 2, swz1);
    b[3][0] = RD_B(odb, 3, swz0); b[3][1] = RD_B(odb, 3, swz1);
    MFMA_Q(4, 0)
    b[0][0] = RD_B(odb, 0, swz0); b[0][1] = RD_B(odb, 0, swz1);
    b[1][0] = RD_B(odb, 1, swz0); b[1][1] = RD_B(odb, 1, swz1);
    STAGE(sd + 1, 1, tA, Asrc);
  }
#undef STAGE
#undef RD_A
#undef RD_B
#undef MFMA_Q

  // ---- epilogue 0 (CARRY, v-columns): in-register intra-chunk EMA prefix ----
  // Chunk q rows (within wave): m=2q holds rows lh*4+r, m=2q+1 rows 16+lh*4+r.
  if constexpr (CARRY) {
    if (bn >= 1024 && bn < 2048) {
      const float l2h = lamlog[((bn - 1024) + wc * 64) >> 6];
      const float lp1 = exp2f(l2h);
      const float lp2 = lp1 * lp1, lp3 = lp2 * lp1, lp4 = lp2 * lp2;
      const float l8 = lp4 * lp4;
      const float lpl = exp2f(l2h * (float)(4 * lh));   // lam^{4*lh}
      #pragma unroll
      for (int q = 0; q < 4; ++q)
        #pragma unroll
        for (int n = 0; n < 4; ++n) {
          f32x4 A0 = acc[2 * q][n], A1 = acc[2 * q + 1][n];
          // in-lane prefix over r (4 contiguous rows)
          A0[1] += lp1 * A0[0]; A0[2] += lp1 * A0[1]; A0[3] += lp1 * A0[2];
          A1[1] += lp1 * A1[0]; A1[2] += lp1 * A1[1]; A1[3] += lp1 * A1[2];
          // cross-lh scan (4 groups of 4 rows), ratio lam^4
          float S = A0[3], x;
          x = __shfl_up(S, 16); if (lh >= 1) S += lp4 * x;
          x = __shfl_up(S, 32); if (lh >= 2) S += l8 * x;
          float Xc = __shfl_up(S, 16); Xc = (lh >= 1) ? Xc : 0.f;  // S_{g-1}
          A0[0] += lp1 * Xc; A0[1] += lp2 * Xc; A0[2] += lp3 * Xc; A0[3] += lp4 * Xc;
          // full prefix through row 15 (lh=3, r=3 of first half)
          float f15 = __shfl(A0[3], 48 + ln15);
          // second half: same cross-lh scan + cross-half carry
          S = A1[3];
          x = __shfl_up(S, 16); if (lh >= 1) S += lp4 * x;
          x = __shfl_up(S, 32); if (lh >= 2) S += l8 * x;
          Xc = __shfl_up(S, 16); Xc = (lh >= 1) ? Xc : 0.f;
          Xc += lpl * f15;   // row 16+lh*4+r gets lam^{lh*4+r+1} * f15
          A1[0] += lp1 * Xc; A1[1] += lp2 * Xc; A1[2] += lp3 * Xc; A1[3] += lp4 * Xc;
          acc[2 * q][n] = A0; acc[2 * q + 1][n] = A1;
        }
    }
  }

  // ---- epilogue 1: C write (v-blocks now hold the local prefix s) ----
  #pragma unroll
  for (int m = 0; m < 8; ++m)
    #pragma unroll
    for (int n = 0; n < 4; ++n)
      #pragma unroll
      for (int r = 0; r < 4; ++r) {
        int row = bm + wr * 128 + m * 16 + lh * 4 + r;   // C/D: row=(lane>>4)*4+reg
        int col = bn + wc * 64 + n * 16 + ln15;          //      col=lane&15
        float vv = acc[m][n][r];
        if constexpr (sizeof(OutT) == 2) Out[(size_t)row * N + col] = f2b(vv);
        else                             Out[(size_t)row * N + col] = vv;
      }

  // ---- epilogue 2: chunk totals = prefix at row 31 (lh==3, odd half, r==3) ----
  if constexpr (CARRY) {
    if (bn >= 1024 && bn < 2048 && lh == 3) {
      const int bidx = bm >> 12;                         // batch (4096 rows each)
      const int chunkbase = ((bm & 4095) >> 5) + wr * 4; // 32-row chunks
      const int colbase = (bn - 1024) + wc * 64;         // v-col base
      #pragma unroll
      for (int q = 0; q < 4; ++q)
        #pragma unroll
        for (int n = 0; n < 4; ++n)
          carry[(size_t)(bidx * NCH + chunkbase + q) * D_MODEL +
                colbase + n * 16 + ln15] = acc[2 * q + 1][n][3];
    }
  }
}

// ---------------- carry prefix: c_j = lambda^CHUNK * c_{j-1} + total_j ----------------
__global__ void scan_carry(float* __restrict__ carry, const float* __restrict__ lam,
                           int B, int nch) {
  int idx = blockIdx.x * blockDim.x + threadIdx.x;
  if (idx >= B * D_MODEL) return;
  int b = idx >> 10, col = idx & (D_MODEL - 1);
  float lC = exp2f(lam[NHEAD + (col >> 6)] * (float)CHUNK);
  float c = 0.f;
  #pragma unroll 4
  for (int j = 0; j < nch; ++j) {
    size_t a = ((size_t)(b * nch + j)) * D_MODEL + col;
    c = lC * c + carry[a];
    carry[a] = c;
  }
}

// ---------------- row-parallel q*state + LayerNorm + SiLU gate (wave-per-row) ----------------
// r16: 4 rows per 256-thr block, one WAVE per row, 16 cols/lane via ushort8
// (16B) loads. shfl_xor butterfly only — zero LDS, zero __syncthreads.
// v-slot of qvg holds the intra-chunk prefix s_t (r11 GEMM epilogue), so
// st = s_t + lam^{tl+1} * carry[j-1] — no serial dependence anywhere.
__global__ __launch_bounds__(256) void ew_ln(const u16* __restrict__ qvg,
    const float* __restrict__ carry, const float* __restrict__ lam,
    const float* __restrict__ gamma, const float* __restrict__ lbeta,
    u16* __restrict__ yout, int nch, int ld) {
  const int wave = threadIdx.x >> 6;
  const int lane = threadIdx.x & 63;
  const int row = blockIdx.x * 4 + wave;
  const int b = row >> 12;                // S = 4096
  const int srow = row & 4095;
  const int j = srow >> 5, tl = srow & 31;  // CHUNK = 32
  const int col0 = lane * 16;
  const size_t rb = (size_t)row * ld;

  u16x8 qu0 = *(const u16x8*)(qvg + rb + col0);
  u16x8 qu1 = *(const u16x8*)(qvg + rb + col0 + 8);
  u16x8 su0 = *(const u16x8*)(qvg + rb + D_MODEL + col0);
  u16x8 su1 = *(const u16x8*)(qvg + rb + D_MODEL + col0 + 8);
  u16x8 gu0 = *(const u16x8*)(qvg + rb + 2 * D_MODEL + col0);
  u16x8 gu1 = *(const u16x8*)(qvg + rb + 2 * D_MODEL + col0 + 8);

  float st[16];
  #pragma unroll
  for (int i = 0; i < 8; ++i) { st[i] = b2f(su0[i]); st[8 + i] = b2f(su1[i]); }
  if (j > 0) {
    float p = exp2f(lam[NHEAD + (col0 >> 6)] * (float)(tl + 1));  // head-uniform per lane
    const float* cb = carry + ((size_t)(b * nch + j - 1)) * D_MODEL + col0;
    const float4 c0 = *(const float4*)(cb);
    const float4 c1 = *(const float4*)(cb + 4);
    const float4 c2 = *(const float4*)(cb + 8);
    const float4 c3 = *(const float4*)(cb + 12);
    st[0]  += p * c0.x; st[1]  += p * c0.y; st[2]  += p * c0.z; st[3]  += p * c0.w;
    st[4]  += p * c1.x; st[5]  += p * c1.y; st[6]  += p * c1.z; st[7]  += p * c1.w;
    st[8]  += p * c2.x; st[9]  += p * c2.y; st[10] += p * c2.z; st[11] += p * c2.w;
    st[12] += p * c3.x; st[13] += p * c3.y; st[14] += p * c3.z; st[15] += p * c3.w;
  }
  float y[16];
  float sum = 0.f, sumsq = 0.f;
  #pragma unroll
  for (int i = 0; i < 8; ++i) {
    y[i] = b2f(qu0[i]) * st[i];
    y[8 + i] = b2f(qu1[i]) * st[8 + i];
  }
  #pragma unroll
  for (int i = 0; i < 16; ++i) { sum += y[i]; sumsq += y[i] * y[i]; }
  #pragma unroll
  for (int off = 32; off > 0; off >>= 1) {
    sum += __shfl_xor(sum, off);
    sumsq += __shfl_xor(sumsq, off);
  }
  const float mu = sum * (1.f / 1024.f);
  const float var = sumsq * (1.f / 1024.f) - mu * mu;
  const float rstd = rsqrtf(var + LN_EPS);

  u16x8 o0, o1;
  #pragma unroll
  for (int i = 0; i < 8; ++i) {
    float gm = gamma[col0 + i], bt = lbeta[col0 + i];
    float g = b2f(gu0[i]);
    o0[i] = f2b(((y[i] - mu) * rstd * gm + bt) * (g / (1.f + __expf(-g))));
    gm = gamma[col0 + 8 + i]; bt = lbeta[col0 + 8 + i];
    g = b2f(gu1[i]);
    o1[i] = f2b(((y[8 + i] - mu) * rstd * gm + bt) * (g / (1.f + __expf(-g))));
  }
  *(u16x8*)(yout + (size_t)row * D_MODEL + col0) = o0;
  *(u16x8*)(yout + (size_t)row * D_MODEL + col0 + 8) = o1;
}

extern "C" void kernel_launch(void* const* d_in, const int* in_sizes, int n_in,
                              void* d_out, int out_size, void* d_ws, size_t ws_size,
                              hipStream_t stream) {
  const float* x     = (const float*)d_in[0];
  const float* Wq    = (const float*)d_in[1];
  const float* Wv    = (const float*)d_in[2];
  const float* Wo    = (const float*)d_in[3];
  const float* Wg    = (const float*)d_in[4];
  const float* beta  = (const float*)d_in[5];
  const float* gamma = (const float*)d_in[6];
  const float* lbeta = (const float*)d_in[7];
  float* out = (float*)d_out;

  const int BS = in_sizes[0] / D_MODEL;     // 16384
  const int B = BS / S_LEN;                  // 4
  const int nch = NCH;                       // 128
  const size_t nx = (size_t)BS * D_MODEL;
  const size_t nw = (size_t)D_MODEL * D_MODEL;
  const int N3 = 3 * D_MODEL;                // 3072

  char* w = (char*)d_ws;
  u16* xb   = (u16*)w;  w += nx * 2;
  u16* wqvg = (u16*)w;  w += 3 * nw * 2;     // packed [Wq;Wv;Wg] rows
  u16* wob  = (u16*)w;  w += nw * 2;
  u16* qvg  = (u16*)w;  w += (size_t)BS * N3 * 2;   // packed [q|s|g] per row
  u16* yb   = (u16*)w;  w += nx * 2;
  float* carry = (float*)w;  w += (size_t)B * nch * D_MODEL * 4;
  float* lam = (float*)w;

  cvt_all<<<2048, 256, 0, stream>>>((const float4*)x, (const float4*)Wq,
      (const float4*)Wv, (const float4*)Wg, (const float4*)Wo,
      (ushort4*)xb, (ushort4*)wqvg, (ushort4*)wob, beta, lam,
      (int)(nx / 4), (int)(nw / 4));

  dim3 g1(BS / 256, N3 / 256);      // 64 x 12
  gemm256<u16, true><<<g1, 512, 0, stream>>>(xb, wqvg, qvg, carry, lam + NHEAD,
                                             BS, N3, D_MODEL);

  scan_carry<<<(B * D_MODEL + 255) / 256, 256, 0, stream>>>(carry, lam, B, nch);
  ew_ln<<<BS / 4, 256, 0, stream>>>(qvg, carry, lam, gamma, lbeta, yb, nch, N3);

  dim3 g2(BS / 256, D_MODEL / 256); // 64 x 4
  gemm256<float, false><<<g2, 512, 0, stream>>>(yb, wob, out, nullptr, nullptr,
                                                BS, D_MODEL, D_MODEL);
}